// Round 1
// baseline (30430.884 us; speedup 1.0000x reference)
//
#include <hip/hip_runtime.h>
#include <math.h>

// Problem constants: S=1024, B=64, I=512, H=512, 2 layers, fp32.
#define SEQ 1024
#define BATCH 64
#define HID 512
#define MROWS (SEQ * BATCH)   // 65536

// ---------------------------------------------------------------------------
// Transpose W_hh (H,H) row-major (j,k) -> Wt[k*H + j] so recurrence reads are
// coalesced across j (lane index).
// ---------------------------------------------------------------------------
__launch_bounds__(256)
__global__ void transposeW(const float* __restrict__ W, float* __restrict__ Wt) {
    __shared__ float tile[32][33];
    int bx = blockIdx.x % 16;           // col-tile
    int by = blockIdx.x / 16;           // row-tile
    int tx = threadIdx.x % 32;
    int ty = threadIdx.x / 32;          // 0..7
    #pragma unroll
    for (int i = 0; i < 32; i += 8)
        tile[ty + i][tx] = W[(size_t)(by * 32 + ty + i) * HID + bx * 32 + tx];
    __syncthreads();
    #pragma unroll
    for (int i = 0; i < 32; i += 8)
        Wt[(size_t)(bx * 32 + ty + i) * HID + by * 32 + tx] = tile[tx][ty + i];
}

// ---------------------------------------------------------------------------
// C[i,j] = sum_k A[i,k] * W[j,k] + b1[j] + b2[j]
// A: (M,512) row-major. W: (512,512) row-major (j,k). C: (M,512).
// Tiled fp32 GEMM: 64x64 tile per 256-thread block, BK=16, 4x4 micro-tile.
// ---------------------------------------------------------------------------
#define BM 64
#define BN 64
#define BK 16
__launch_bounds__(256)
__global__ void gemm_bias(const float* __restrict__ A, const float* __restrict__ W,
                          const float* __restrict__ b1, const float* __restrict__ b2,
                          float* __restrict__ C) {
    __shared__ float As[BK][BM + 4];
    __shared__ float Ws[BK][BN + 4];

    const int bj = blockIdx.x % (HID / BN);   // 0..7
    const int bi = blockIdx.x / (HID / BN);   // 0..1023
    const int tid = threadIdx.x;
    const int tx = tid % 16;
    const int ty = tid / 16;
    const int row0 = bi * BM;
    const int col0 = bj * BN;

    // loader mapping: each thread loads one float4 of A and one of W per chunk
    const int lr = tid / 4;              // 0..63  (tile row)
    const int lk = (tid % 4) * 4;        // 0,4,8,12 (k offset)

    float acc[4][4] = {};

    for (int k0 = 0; k0 < HID; k0 += BK) {
        float4 av = *(const float4*)(A + (size_t)(row0 + lr) * HID + k0 + lk);
        float4 wv = *(const float4*)(W + (size_t)(col0 + lr) * HID + k0 + lk);
        As[lk + 0][lr] = av.x; As[lk + 1][lr] = av.y;
        As[lk + 2][lr] = av.z; As[lk + 3][lr] = av.w;
        Ws[lk + 0][lr] = wv.x; Ws[lk + 1][lr] = wv.y;
        Ws[lk + 2][lr] = wv.z; Ws[lk + 3][lr] = wv.w;
        __syncthreads();
        #pragma unroll
        for (int k = 0; k < BK; ++k) {
            float4 a = *(const float4*)&As[k][ty * 4];
            float4 w = *(const float4*)&Ws[k][tx * 4];
            acc[0][0] += a.x * w.x; acc[0][1] += a.x * w.y; acc[0][2] += a.x * w.z; acc[0][3] += a.x * w.w;
            acc[1][0] += a.y * w.x; acc[1][1] += a.y * w.y; acc[1][2] += a.y * w.z; acc[1][3] += a.y * w.w;
            acc[2][0] += a.z * w.x; acc[2][1] += a.z * w.y; acc[2][2] += a.z * w.z; acc[2][3] += a.z * w.w;
            acc[3][0] += a.w * w.x; acc[3][1] += a.w * w.y; acc[3][2] += a.w * w.z; acc[3][3] += a.w * w.w;
        }
        __syncthreads();
    }

    #pragma unroll
    for (int c = 0; c < 4; ++c) {
        int col = col0 + tx * 4 + c;
        float bias = b1[col] + b2[col];
        #pragma unroll
        for (int r = 0; r < 4; ++r) {
            C[(size_t)(row0 + ty * 4 + r) * HID + col] = acc[r][c] + bias;
        }
    }
}

// ---------------------------------------------------------------------------
// Persistent recurrence: one workgroup per batch element (batch rows are
// independent -> no inter-WG sync). 256 threads, each owns j = 2*tid, 2*tid+1.
// U (S,B,H) holds the precomputed input transform (incl. both biases);
// overwritten in place with y. Wt is W_hh transposed: Wt[k*H + j].
// ---------------------------------------------------------------------------
__launch_bounds__(256)
__global__ void rnn_rec(float* __restrict__ U, const float* __restrict__ Wt,
                        const float* __restrict__ h0, float* __restrict__ hT) {
    __shared__ float ha[HID], hb[HID];
    const int b = blockIdx.x;
    const int tid = threadIdx.x;
    const int j0 = 2 * tid;
    const int j1 = 2 * tid + 1;

    ha[j0] = h0[(size_t)b * HID + j0];
    ha[j1] = h0[(size_t)b * HID + j1];
    __syncthreads();

    float* cur = ha;
    float* nxt = hb;

    for (int t = 0; t < SEQ; ++t) {
        const size_t base = ((size_t)t * BATCH + b) * HID;
        float2 u = *(const float2*)(U + base + j0);
        float acc0 = u.x;
        float acc1 = u.y;

        for (int k = 0; k < HID; k += 4) {
            float4 h4 = *(const float4*)(cur + k);
            const float* w = Wt + (size_t)k * HID + j0;
            float2 w0 = *(const float2*)(w);
            float2 w1 = *(const float2*)(w + HID);
            float2 w2 = *(const float2*)(w + 2 * HID);
            float2 w3 = *(const float2*)(w + 3 * HID);
            acc0 += h4.x * w0.x; acc1 += h4.x * w0.y;
            acc0 += h4.y * w1.x; acc1 += h4.y * w1.y;
            acc0 += h4.z * w2.x; acc1 += h4.z * w2.y;
            acc0 += h4.w * w3.x; acc1 += h4.w * w3.y;
        }

        float v0 = tanhf(acc0);
        float v1 = tanhf(acc1);
        *(float2*)(U + base + j0) = make_float2(v0, v1);
        nxt[j0] = v0;
        nxt[j1] = v1;
        __syncthreads();
        float* tmp = cur; cur = nxt; nxt = tmp;
    }

    hT[(size_t)b * HID + j0] = cur[j0];
    hT[(size_t)b * HID + j1] = cur[j1];
}

// ---------------------------------------------------------------------------
// Launch
// ---------------------------------------------------------------------------
extern "C" void kernel_launch(void* const* d_in, const int* in_sizes, int n_in,
                              void* d_out, int out_size, void* d_ws, size_t ws_size,
                              hipStream_t stream) {
    (void)in_sizes; (void)n_in; (void)out_size; (void)ws_size;

    const float* x      = (const float*)d_in[0];   // (S,B,I)
    const float* hx     = (const float*)d_in[1];   // (2,B,H)
    const float* W_ih0  = (const float*)d_in[2];   // (H,I)
    const float* W_hh0  = (const float*)d_in[3];   // (H,H)
    const float* b_ih0  = (const float*)d_in[4];   // (H,)
    const float* b_hh0  = (const float*)d_in[5];   // (H,)
    const float* W_ih1  = (const float*)d_in[6];   // (H,H)
    const float* W_hh1  = (const float*)d_in[7];   // (H,H)
    const float* b_ih1  = (const float*)d_in[8];   // (H,)
    const float* b_hh1  = (const float*)d_in[9];   // (H,)

    float* out = (float*)d_out;
    float* y1   = out;                                  // (S,B,H) = 33554432
    float* hT0  = out + (size_t)SEQ * BATCH * HID;      // (B,H)
    float* hT1  = hT0 + (size_t)BATCH * HID;            // (B,H)

    // Workspace layout: Wt0 (1MB) | Wt1 (1MB) | U0/y0 (134MB)
    float* Wt0 = (float*)d_ws;
    float* Wt1 = Wt0 + (size_t)HID * HID;
    float* U0  = Wt1 + (size_t)HID * HID;

    // 1. transpose W_hh for both layers
    transposeW<<<256, 256, 0, stream>>>(W_hh0, Wt0);
    transposeW<<<256, 256, 0, stream>>>(W_hh1, Wt1);

    // 2. Layer 0 input GEMM: U0 = x @ W_ih0^T + b_ih0 + b_hh0
    gemm_bias<<<(MROWS / BM) * (HID / BN), 256, 0, stream>>>(x, W_ih0, b_ih0, b_hh0, U0);

    // 3. Layer 0 recurrence (writes y0 in place into U0, final hidden to hT0)
    rnn_rec<<<BATCH, 256, 0, stream>>>(U0, Wt0, hx, hT0);

    // 4. Layer 1 input GEMM: U1 = y0 @ W_ih1^T + b_ih1 + b_hh1 -> into d_out y1 region
    gemm_bias<<<(MROWS / BM) * (HID / BN), 256, 0, stream>>>(U0, W_ih1, b_ih1, b_hh1, y1);

    // 5. Layer 1 recurrence (writes y1 in place, final hidden to hT1)
    rnn_rec<<<BATCH, 256, 0, stream>>>(y1, Wt1, hx + (size_t)BATCH * HID, hT1);
}